// Round 1
// baseline (2447.691 us; speedup 1.0000x reference)
//
#include <hip/hip_runtime.h>
#include <cfloat>

#define B_  8
#define N_  2048
#define H_  256
#define L_  4
#define K_  16
#define G_  512
#define M0_ 256
#define M1_ 128
#define C_  128
#define BN_ 16384   // B_*N_

// ---------------- workspace layout (bytes) ----------------
#define OFF_H     ((size_t)0)
#define OFF_T     ((size_t)16777216)
#define OFF_U     ((size_t)33554432)
#define OFF_V     ((size_t)50331648)
#define OFF_XB    ((size_t)67108864)
#define OFF_SQ    ((size_t)83886080)   // 16384 floats
#define OFF_IDX   ((size_t)83951616)   // 16384*16 ints
#define OFF_WC    ((size_t)85000192)   // 4*256*256 floats
#define OFF_STATS ((size_t)86048768)   // 512 doubles
#define OFF_SCSH  ((size_t)86052864)   // 512 floats
#define OFF_P0    ((size_t)86054912)   // 8*512 floats
#define OFF_P1    ((size_t)86071296)   // 8*256 floats
#define OFF_P2    ((size_t)86079488)   // 8*128 floats
#define OFF_D     ((size_t)86083584)   // 8*2048*2048 floats (reused for y, pmax)
#define WS_NEEDED ((size_t)220301312)

// ---------------- kernels ----------------

// Wcomb[l] = We[l][0:H] - We[l][H:2H]   (so msg = x@Wcomb + be + (x@We_b)[j])
__global__ void wcomb_kernel(const float* __restrict__ We, float* __restrict__ Wc) {
    int i = blockIdx.x * 256 + threadIdx.x;       // 0 .. 4*65536-1
    int l = i >> 16;
    int rc = i & 0xffff;
    size_t base = (size_t)l * 2 * H_ * H_;
    Wc[i] = We[base + rc] - We[base + (size_t)H_ * H_ + rc];
}

// h = x @ Wf + bf   (x: (BN,3))
__global__ void feat_kernel(const float* __restrict__ x, const float* __restrict__ Wf,
                            const float* __restrict__ bf, float* __restrict__ h) {
    int pt = blockIdx.x;
    int f  = threadIdx.x;
    float x0 = x[pt * 3 + 0], x1 = x[pt * 3 + 1], x2 = x[pt * 3 + 2];
    h[(size_t)pt * H_ + f] = x0 * Wf[f] + x1 * Wf[H_ + f] + x2 * Wf[2 * H_ + f] + bf[f];
}

// generic fp32 GEMM: C = A(MxK) @ B(KxN) (+bias)   M,N multiples of 64, K multiple of 16
__global__ __launch_bounds__(256) void gemm64(const float* __restrict__ A,
                                              const float* __restrict__ Bm,
                                              const float* __restrict__ bias,
                                              float* __restrict__ Cc,
                                              int M, int Kd, int Nd) {
    __shared__ __align__(16) float As[16][68];
    __shared__ __align__(16) float Bs[16][68];
    int tid = threadIdx.x;
    int tx = tid & 15, ty = tid >> 4;
    int row0 = blockIdx.y * 64;
    int col0 = blockIdx.x * 64;
    int arow = tid >> 2;         // 0..63
    int ak   = (tid & 3) * 4;    // 0,4,8,12
    int bcol = tid & 63;         // 0..63
    int bk0  = tid >> 6;         // 0..3
    float acc[4][4] = {};
    for (int k0 = 0; k0 < Kd; k0 += 16) {
        float4 av = *(const float4*)(A + (size_t)(row0 + arow) * Kd + k0 + ak);
        As[ak + 0][arow] = av.x; As[ak + 1][arow] = av.y;
        As[ak + 2][arow] = av.z; As[ak + 3][arow] = av.w;
#pragma unroll
        for (int s = 0; s < 4; ++s) {
            int kk = bk0 + 4 * s;
            Bs[kk][bcol] = Bm[(size_t)(k0 + kk) * Nd + col0 + bcol];
        }
        __syncthreads();
#pragma unroll
        for (int k = 0; k < 16; ++k) {
            float4 a4 = *(const float4*)&As[k][ty * 4];
            float4 b4 = *(const float4*)&Bs[k][tx * 4];
            float a[4] = {a4.x, a4.y, a4.z, a4.w};
            float b[4] = {b4.x, b4.y, b4.z, b4.w};
#pragma unroll
            for (int i = 0; i < 4; ++i)
#pragma unroll
                for (int j = 0; j < 4; ++j) acc[i][j] += a[i] * b[j];
        }
        __syncthreads();
    }
#pragma unroll
    for (int i = 0; i < 4; ++i) {
        int r = row0 + ty * 4 + i;
        int c = col0 + tx * 4;
        float4 o;
        float b0 = bias ? bias[c + 0] : 0.f, b1 = bias ? bias[c + 1] : 0.f;
        float b2 = bias ? bias[c + 2] : 0.f, b3 = bias ? bias[c + 3] : 0.f;
        o.x = acc[i][0] + b0; o.y = acc[i][1] + b1;
        o.z = acc[i][2] + b2; o.w = acc[i][3] + b3;
        *(float4*)(Cc + (size_t)r * Nd + c) = o;
    }
}

// per-point squared norm
__global__ void sqnorm(const float* __restrict__ X, float* __restrict__ sq) {
    int w = threadIdx.x >> 6, lane = threadIdx.x & 63;
    int pt = blockIdx.x * 4 + w;
    const float* xp = X + (size_t)pt * H_;
    float s = 0.f;
    for (int k = lane; k < H_; k += 64) { float v = xp[k]; s += v * v; }
#pragma unroll
    for (int off = 32; off; off >>= 1) s += __shfl_down(s, off);
    if (lane == 0) sq[pt] = s;
}

// D[b,i,j] = sq[b,j] - 2 * <x_i, x_j>   (sq[i] omitted: constant per row, rank-preserving)
__global__ __launch_bounds__(256) void gram64(const float* __restrict__ X,
                                              const float* __restrict__ sq,
                                              float* __restrict__ D) {
    int bz = blockIdx.z;
    const float* Xb  = X  + (size_t)bz * N_ * H_;
    const float* sqb = sq + (size_t)bz * N_;
    __shared__ __align__(16) float As[16][68];
    __shared__ __align__(16) float Bs[16][68];
    int tid = threadIdx.x;
    int tx = tid & 15, ty = tid >> 4;
    int i0 = blockIdx.y * 64, j0 = blockIdx.x * 64;
    int arow = tid >> 2;
    int ak   = (tid & 3) * 4;
    float acc[4][4] = {};
    for (int k0 = 0; k0 < H_; k0 += 16) {
        float4 av = *(const float4*)(Xb + (size_t)(i0 + arow) * H_ + k0 + ak);
        float4 bv = *(const float4*)(Xb + (size_t)(j0 + arow) * H_ + k0 + ak);
        As[ak + 0][arow] = av.x; As[ak + 1][arow] = av.y;
        As[ak + 2][arow] = av.z; As[ak + 3][arow] = av.w;
        Bs[ak + 0][arow] = bv.x; Bs[ak + 1][arow] = bv.y;
        Bs[ak + 2][arow] = bv.z; Bs[ak + 3][arow] = bv.w;
        __syncthreads();
#pragma unroll
        for (int k = 0; k < 16; ++k) {
            float4 a4 = *(const float4*)&As[k][ty * 4];
            float4 b4 = *(const float4*)&Bs[k][tx * 4];
            float a[4] = {a4.x, a4.y, a4.z, a4.w};
            float b[4] = {b4.x, b4.y, b4.z, b4.w};
#pragma unroll
            for (int i = 0; i < 4; ++i)
#pragma unroll
                for (int j = 0; j < 4; ++j) acc[i][j] += a[i] * b[j];
        }
        __syncthreads();
    }
    float4 sqv = *(const float4*)(sqb + j0 + tx * 4);
    float sqa[4] = {sqv.x, sqv.y, sqv.z, sqv.w};
#pragma unroll
    for (int i = 0; i < 4; ++i) {
        int r = i0 + ty * 4 + i;
        int c = j0 + tx * 4;
        float4 o;
        o.x = sqa[0] - 2.f * acc[i][0];
        o.y = sqa[1] - 2.f * acc[i][1];
        o.z = sqa[2] - 2.f * acc[i][2];
        o.w = sqa[3] - 2.f * acc[i][3];
        *(float4*)(D + (size_t)bz * N_ * N_ + (size_t)r * N_ + c) = o;
    }
}

// wave-per-row top-16 smallest (ties -> smaller index, matching XLA top_k)
__global__ __launch_bounds__(256) void topk16(const float* __restrict__ D,
                                              int* __restrict__ idxb) {
    int w = threadIdx.x >> 6, lane = threadIdx.x & 63;
    int row = blockIdx.x * 4 + w;            // 0..16383  (= b*N + i)
    const float* dp = D + (size_t)row * N_;
    float lv[32];
#pragma unroll
    for (int t = 0; t < 32; ++t) lv[t] = dp[lane + (t << 6)];
    unsigned mask = 0;
    for (int it = 0; it < 16; ++it) {
        float bv = FLT_MAX;
        int bt = 0;
#pragma unroll
        for (int t = 0; t < 32; ++t) {
            bool ok = (((mask >> t) & 1u) == 0u) && (lv[t] < bv);
            bv = ok ? lv[t] : bv;
            bt = ok ? t : bt;
        }
        unsigned sb = __float_as_uint(bv);
        sb = (sb & 0x80000000u) ? ~sb : (sb | 0x80000000u);
        unsigned j = (unsigned)lane + ((unsigned)bt << 6);
        unsigned long long key = ((unsigned long long)sb << 32) | j;
#pragma unroll
        for (int off = 32; off; off >>= 1) {
            unsigned long long o = __shfl_xor(key, off);
            key = (o < key) ? o : key;
        }
        unsigned jw = (unsigned)(key & 0xffffffffu);
        if ((unsigned)lane == (jw & 63u)) mask |= 1u << (jw >> 6);
        if (lane == 0) idxb[row * 16 + it] = (int)jw;
    }
}

// t[b,i,h] = u[b,i,h] + max_k v[b, idx[b,i,k], h]
__global__ void gather_max(const float* __restrict__ u, const float* __restrict__ v,
                           const int* __restrict__ idxb, float* __restrict__ outp) {
    int row = blockIdx.x;           // b*N + i
    int b = row >> 11;
    int h = threadIdx.x;
    const float* vb = v + (((size_t)b) << 11) * H_;
    float m = -FLT_MAX;
#pragma unroll
    for (int k = 0; k < 16; ++k) {
        int j = idxb[row * 16 + k];
        m = fmaxf(m, vb[(size_t)j * H_ + h]);
    }
    size_t i = (size_t)row * H_ + h;
    outp[i] = u[i] + m;
}

// ---- batchnorm over (B,N) per feature ----
__global__ void bn_zero(double* s) { s[threadIdx.x] = 0.0; }

__global__ void bn_stats(const float* __restrict__ X, double* __restrict__ sums) {
    int f = threadIdx.x;
    int r0 = blockIdx.x * 64;
    double s = 0.0, s2 = 0.0;
    for (int r = 0; r < 64; ++r) {
        float v = X[(size_t)(r0 + r) * H_ + f];
        s += v; s2 += (double)v * v;
    }
    atomicAdd(&sums[f], s);
    atomicAdd(&sums[H_ + f], s2);
}

__global__ void bn_final(const double* __restrict__ sums, const float* __restrict__ g,
                         const float* __restrict__ b, float* __restrict__ scsh) {
    int f = threadIdx.x;
    double m  = sums[f] / (double)BN_;
    double var = sums[H_ + f] / (double)BN_ - m * m;
    double inv = 1.0 / sqrt(var + 1e-5);
    float sc = g[f] * (float)inv;
    scsh[f] = sc;
    scsh[H_ + f] = b[f] - (float)m * sc;
}

__global__ void bn_apply_relu(const float* __restrict__ X, const float* __restrict__ scsh,
                              float* __restrict__ Y) {
    size_t i = (size_t)blockIdx.x * H_ + threadIdx.x;
    float v = X[i] * scsh[threadIdx.x] + scsh[H_ + threadIdx.x];
    Y[i] = fmaxf(v, 0.f);
}

__global__ void residual_kernel(float* __restrict__ h, const float* __restrict__ t,
                                const float* __restrict__ alpha, int l) {
    size_t i = (size_t)blockIdx.x * H_ + threadIdx.x;
    h[i] += alpha[l] * t[i];
}

// global max over N: stage 1 (128-row chunks)
__global__ void maxpool1(const float* __restrict__ y, float* __restrict__ pmax) {
    int b = blockIdx.x, gc = blockIdx.y, nc = blockIdx.z;
    int g = gc * 256 + threadIdx.x;
    const float* yb = y + ((size_t)b * N_ + (size_t)nc * 128) * G_;
    float m = -FLT_MAX;
    for (int n = 0; n < 128; ++n) m = fmaxf(m, yb[(size_t)n * G_ + g]);
    pmax[((size_t)(b * 16 + nc)) * G_ + g] = m;
}

__global__ void maxpool2(const float* __restrict__ pmax, float* __restrict__ p) {
    int b = blockIdx.x;
    int g = blockIdx.y * 256 + threadIdx.x;
    float m = -FLT_MAX;
    for (int c = 0; c < 16; ++c) m = fmaxf(m, pmax[((size_t)(b * 16 + c)) * G_ + g]);
    p[(size_t)b * G_ + g] = m;
}

// tiny MLP gemm: one block per output row, one thread per output col
__global__ void small_gemm(const float* __restrict__ A, const float* __restrict__ W,
                           const float* __restrict__ bias, float* __restrict__ Cc,
                           int Kd, int Nd, int relu) {
    int m = blockIdx.x;
    int c = threadIdx.x;
    float acc = 0.f;
    for (int k = 0; k < Kd; ++k) acc += A[m * Kd + k] * W[(size_t)k * Nd + c];
    acc += bias[c];
    if (relu) acc = fmaxf(acc, 0.f);
    Cc[(size_t)m * Nd + c] = acc;
}

// ---------------- launch ----------------
extern "C" void kernel_launch(void* const* d_in, const int* in_sizes, int n_in,
                              void* d_out, int out_size, void* d_ws, size_t ws_size,
                              hipStream_t stream) {
    (void)in_sizes; (void)n_in; (void)out_size;
    if (ws_size < WS_NEEDED) return;

    const float* x    = (const float*)d_in[0];
    const float* Wf   = (const float*)d_in[2];
    const float* bf   = (const float*)d_in[3];
    const float* Wnn  = (const float*)d_in[4];
    const float* bnn  = (const float*)d_in[5];
    const float* g1   = (const float*)d_in[6];
    const float* b1   = (const float*)d_in[7];
    const float* We   = (const float*)d_in[8];
    const float* be   = (const float*)d_in[9];
    const float* g2   = (const float*)d_in[10];
    const float* b2   = (const float*)d_in[11];
    const float* Wl   = (const float*)d_in[12];
    const float* bl   = (const float*)d_in[13];
    const float* alpha= (const float*)d_in[14];
    const float* gg   = (const float*)d_in[15];
    const float* bgb  = (const float*)d_in[16];
    const float* Wg   = (const float*)d_in[17];
    const float* bg2  = (const float*)d_in[18];
    const float* Wm1  = (const float*)d_in[19];
    const float* bm1  = (const float*)d_in[20];
    const float* Wm2  = (const float*)d_in[21];
    const float* bm2  = (const float*)d_in[22];
    const float* Wm3  = (const float*)d_in[23];
    const float* bm3  = (const float*)d_in[24];
    float* outp = (float*)d_out;

    char* ws = (char*)d_ws;
    float*  h    = (float*)(ws + OFF_H);
    float*  t    = (float*)(ws + OFF_T);
    float*  u    = (float*)(ws + OFF_U);
    float*  v    = (float*)(ws + OFF_V);
    float*  xb   = (float*)(ws + OFF_XB);
    float*  sqb  = (float*)(ws + OFF_SQ);
    int*    idxb = (int*)  (ws + OFF_IDX);
    float*  wc   = (float*)(ws + OFF_WC);
    double* stats= (double*)(ws + OFF_STATS);
    float*  scsh = (float*)(ws + OFF_SCSH);
    float*  p0   = (float*)(ws + OFF_P0);
    float*  p1   = (float*)(ws + OFF_P1);
    float*  p2   = (float*)(ws + OFF_P2);
    float*  dmat = (float*)(ws + OFF_D);
    float*  y    = dmat;                             // reuse after dgcnn done
    float*  pmax = (float*)(ws + OFF_D + 33554432);  // after y

    auto run_bn = [&](const float* src, const float* g, const float* b, float* dst) {
        hipLaunchKernelGGL(bn_zero, dim3(1), dim3(512), 0, stream, stats);
        hipLaunchKernelGGL(bn_stats, dim3(256), dim3(256), 0, stream, src, stats);
        hipLaunchKernelGGL(bn_final, dim3(1), dim3(256), 0, stream, stats, g, b, scsh);
        hipLaunchKernelGGL(bn_apply_relu, dim3(BN_), dim3(256), 0, stream, src, scsh, dst);
    };

    hipLaunchKernelGGL(wcomb_kernel, dim3(1024), dim3(256), 0, stream, We, wc);
    hipLaunchKernelGGL(feat_kernel, dim3(BN_), dim3(256), 0, stream, x, Wf, bf, h);
    // layer 0 pre-transform
    hipLaunchKernelGGL(gemm64, dim3(4, 256), dim3(256), 0, stream, h, Wnn, bnn, t,
                       BN_, H_, H_);

    for (int l = 0; l < L_; ++l) {
        run_bn(l == 0 ? t : h, g1 + l * H_, b1 + l * H_, xb);
        hipLaunchKernelGGL(sqnorm, dim3(BN_ / 4), dim3(256), 0, stream, xb, sqb);
        hipLaunchKernelGGL(gram64, dim3(32, 32, 8), dim3(256), 0, stream, xb, sqb, dmat);
        hipLaunchKernelGGL(topk16, dim3(BN_ / 4), dim3(256), 0, stream, dmat, idxb);
        hipLaunchKernelGGL(gemm64, dim3(4, 256), dim3(256), 0, stream,
                           xb, wc + (size_t)l * H_ * H_, be + l * H_, u, BN_, H_, H_);
        hipLaunchKernelGGL(gemm64, dim3(4, 256), dim3(256), 0, stream,
                           xb, We + (size_t)l * 2 * H_ * H_ + (size_t)H_ * H_, (const float*)nullptr,
                           v, BN_, H_, H_);
        hipLaunchKernelGGL(gather_max, dim3(BN_), dim3(256), 0, stream, u, v, idxb, t);
        run_bn(t, g2 + l * H_, b2 + l * H_, xb);
        hipLaunchKernelGGL(gemm64, dim3(4, 256), dim3(256), 0, stream,
                           xb, Wl + (size_t)l * H_ * H_, bl + l * H_, u, BN_, H_, H_);
        hipLaunchKernelGGL(residual_kernel, dim3(BN_), dim3(256), 0, stream, h, u, alpha, l);
    }

    run_bn(h, gg, bgb, xb);
    hipLaunchKernelGGL(gemm64, dim3(8, 256), dim3(256), 0, stream, xb, Wg, bg2, y,
                       BN_, H_, G_);
    hipLaunchKernelGGL(maxpool1, dim3(8, 2, 16), dim3(256), 0, stream, y, pmax);
    hipLaunchKernelGGL(maxpool2, dim3(8, 2), dim3(256), 0, stream, pmax, p0);
    hipLaunchKernelGGL(small_gemm, dim3(8), dim3(256), 0, stream, p0, Wm1, bm1, p1, G_, M0_, 1);
    hipLaunchKernelGGL(small_gemm, dim3(8), dim3(128), 0, stream, p1, Wm2, bm2, p2, M0_, M1_, 1);
    hipLaunchKernelGGL(small_gemm, dim3(8), dim3(128), 0, stream, p2, Wm3, bm3, outp, M1_, C_, 0);
}

// Round 2
// 1703.052 us; speedup vs baseline: 1.4372x; 1.4372x over previous
//
#include <hip/hip_runtime.h>
#include <cfloat>

#define B_  8
#define N_  2048
#define H_  256
#define L_  4
#define K_  16
#define G_  512
#define M0_ 256
#define M1_ 128
#define C_  128
#define BN_ 16384   // B_*N_
#define KP_ 768     // packed split-bf16 K (3*H_)

typedef unsigned short ushort_t;
typedef __attribute__((ext_vector_type(8))) short short8;
typedef __attribute__((ext_vector_type(4))) float f32x4;

// ---------------- workspace layout (bytes) ----------------
#define OFF_H     ((size_t)0)            // 16 MB  h (fp32, persistent)
#define OFF_APACK ((size_t)16777216)     // 25.2 MB  P-pack [hi,lo,hi]
#define OFF_BPACK ((size_t)41943040)     // 25.2 MB  Q-pack [hi,hi,lo] (gram)
#define OFF_SQ    ((size_t)67108864)     // 64 KB
#define OFF_IDX   ((size_t)67174400)     // 1 MB
#define OFF_STATS ((size_t)68222976)     // 4 KB (512 doubles)
#define OFF_SCSH  ((size_t)68227072)     // 2 KB
#define OFF_BCAT  ((size_t)68229120)     // 2 KB
#define OFF_P0    ((size_t)68231168)     // 16 KB
#define OFF_P1    ((size_t)68247552)
#define OFF_P2    ((size_t)68255744)
#define OFF_D     ((size_t)69206016)     // 134.2 MB dmat; region multiplexed below
#define OFF_T     (OFF_D + (size_t)0)           // 16 MB (alive gather_max -> bn2)
#define OFF_U     (OFF_D + (size_t)16777216)    // 16 MB (alive Wl gemm -> residual)
#define OFF_XB    (OFF_D + (size_t)33554432)    // 16 MB (alive bn1 -> sqnorm)
#define OFF_UV    (OFF_D + (size_t)50331648)    // 33.5 MB (alive uv gemm -> gather); also y
#define OFF_QW    (OFF_D + (size_t)83886080)    // 0.79 MB weight packs (lazy, post-topk)
#define OFF_PMAX  (OFF_D + (size_t)84672512)    // 256 KB
#define WS_NEEDED ((size_t)203423744)

// ---------------- helpers ----------------
static __device__ __forceinline__ ushort_t f2bf(float f) {
    unsigned u = __float_as_uint(f);
    unsigned r = (u + 0x7fffu + ((u >> 16) & 1u)) >> 16;   // RNE
    return (ushort_t)r;
}
static __device__ __forceinline__ float bf2f(ushort_t h) {
    return __uint_as_float(((unsigned)h) << 16);
}
static __device__ __forceinline__ void pack3(float v, ushort_t* A, ushort_t* Bq,
                                             size_t base, int f) {
    ushort_t hi = f2bf(v);
    ushort_t lo = f2bf(v - bf2f(hi));
    A[base + f] = hi; A[base + H_ + f] = lo; A[base + 2 * H_ + f] = hi;
    if (Bq) { Bq[base + f] = hi; Bq[base + H_ + f] = hi; Bq[base + 2 * H_ + f] = lo; }
}

// ---------------- kernels ----------------

// h = x @ Wf + bf ; also pack h into Apack
__global__ void feat_pack(const float* __restrict__ x, const float* __restrict__ Wf,
                          const float* __restrict__ bfv, float* __restrict__ h,
                          ushort_t* __restrict__ Ap) {
    int pt = blockIdx.x;
    int f  = threadIdx.x;
    float x0 = x[pt * 3 + 0], x1 = x[pt * 3 + 1], x2 = x[pt * 3 + 2];
    float v = x0 * Wf[f] + x1 * Wf[H_ + f] + x2 * Wf[2 * H_ + f] + bfv[f];
    h[(size_t)pt * H_ + f] = v;
    pack3(v, Ap, nullptr, (size_t)pt * KP_, f);
}

// W (256 x Nd) -> Qpack (Nd x 768) rows [hi,hi,lo] of W^T
__global__ void pack_wT(const float* __restrict__ W, ushort_t* __restrict__ Qp, int Nd) {
    int n = blockIdx.x, k = threadIdx.x;
    float w = W[(size_t)k * Nd + n];
    ushort_t hi = f2bf(w), lo = f2bf(w - bf2f(hi));
    size_t base = (size_t)n * KP_;
    Qp[base + k] = hi; Qp[base + H_ + k] = hi; Qp[base + 2 * H_ + k] = lo;
}

// Qcat for fused u|v gemm: rows 0..255 = (We_a - We_b)^T, rows 256..511 = We_b^T
__global__ void pack_qcat(const float* __restrict__ We_l, const float* __restrict__ be_l,
                          ushort_t* __restrict__ Qp, float* __restrict__ bcat) {
    int n = blockIdx.x, k = threadIdx.x;
    float w;
    if (n < H_) w = We_l[(size_t)k * H_ + n] - We_l[(size_t)H_ * H_ + (size_t)k * H_ + n];
    else        w = We_l[(size_t)H_ * H_ + (size_t)k * H_ + (n - H_)];
    ushort_t hi = f2bf(w), lo = f2bf(w - bf2f(hi));
    size_t base = (size_t)n * KP_;
    Qp[base + k] = hi; Qp[base + H_ + k] = hi; Qp[base + 2 * H_ + k] = lo;
    if (k == 0) bcat[n] = (n < H_) ? be_l[n] : 0.f;
}

// ---- split-bf16 MFMA GEMM: out = P (M x K) . Q^T (N x K) ----
// mode 0: out[r][c] = acc + aux[c]           (dense, aux = bias)
// mode 1: out[r][c] = aux[c] - 2*acc         (gram,  aux = sq)
__global__ __launch_bounds__(256) void mfma_gemm(
    const ushort_t* __restrict__ P, const ushort_t* __restrict__ Q,
    const float* __restrict__ aux, float* __restrict__ out,
    int Kd, int ldOut,
    long long strideP, long long strideQ, long long strideOut, long long strideAux,
    int mode) {
    __shared__ __align__(16) ushort_t As[128 * 32];
    __shared__ __align__(16) ushort_t Bs[128 * 32];
    int z = blockIdx.z;
    P   += (size_t)z * strideP;
    Q   += (size_t)z * strideQ;
    out += (size_t)z * strideOut;
    aux += (size_t)z * strideAux;
    int i0 = blockIdx.y * 128, j0 = blockIdx.x * 128;
    int tid = threadIdx.x;
    int lane = tid & 63, wave = tid >> 6;
    int wm = wave & 1, wn = wave >> 1;
    int m16 = lane & 15, kq = (lane >> 4) * 8;

    f32x4 acc[4][4];
    f32x4 zero = {0.f, 0.f, 0.f, 0.f};
#pragma unroll
    for (int i = 0; i < 4; ++i)
#pragma unroll
        for (int j = 0; j < 4; ++j) acc[i][j] = zero;

    int srow = tid >> 2;           // 0..63  (chunk row for s=0)
    int skc  = (tid & 3) * 8;      // k element offset of 16B chunk

    for (int k0 = 0; k0 < Kd; k0 += 32) {
#pragma unroll
        for (int s = 0; s < 2; ++s) {
            int row = srow + s * 64;
            const ushort_t* gpA = P + (size_t)(i0 + row) * Kd + k0 + skc;
            const ushort_t* gpB = Q + (size_t)(j0 + row) * Kd + k0 + skc;
            __builtin_amdgcn_global_load_lds(
                (const __attribute__((address_space(1))) void*)gpA,
                (__attribute__((address_space(3))) void*)(As + (size_t)(wave * 64 + s * 256) * 8),
                16, 0, 0);
            __builtin_amdgcn_global_load_lds(
                (const __attribute__((address_space(1))) void*)gpB,
                (__attribute__((address_space(3))) void*)(Bs + (size_t)(wave * 64 + s * 256) * 8),
                16, 0, 0);
        }
        __syncthreads();
        short8 af[4], bfr[4];
#pragma unroll
        for (int fi = 0; fi < 4; ++fi)
            af[fi] = *(const short8*)(As + (wm * 64 + fi * 16 + m16) * 32 + kq);
#pragma unroll
        for (int fj = 0; fj < 4; ++fj)
            bfr[fj] = *(const short8*)(Bs + (wn * 64 + fj * 16 + m16) * 32 + kq);
#pragma unroll
        for (int fi = 0; fi < 4; ++fi)
#pragma unroll
            for (int fj = 0; fj < 4; ++fj)
                acc[fi][fj] = __builtin_amdgcn_mfma_f32_16x16x32_bf16(
                    af[fi], bfr[fj], acc[fi][fj], 0, 0, 0);
        __syncthreads();
    }
    // C/D layout: col = lane&15, row = (lane>>4)*4 + reg
    int rbase = i0 + wm * 64 + (lane >> 4) * 4;
    int cbase = j0 + wn * 64 + m16;
#pragma unroll
    for (int fi = 0; fi < 4; ++fi) {
#pragma unroll
        for (int fj = 0; fj < 4; ++fj) {
            int c = cbase + fj * 16;
            float a = aux[c];
#pragma unroll
            for (int r = 0; r < 4; ++r) {
                int gr = rbase + fi * 16 + r;
                float val = (mode == 1) ? (a - 2.f * acc[fi][fj][r])
                                        : (acc[fi][fj][r] + a);
                out[(size_t)gr * ldOut + c] = val;
            }
        }
    }
}

// per-point squared norm (fp32 activations)
__global__ void sqnorm(const float* __restrict__ X, float* __restrict__ sq) {
    int w = threadIdx.x >> 6, lane = threadIdx.x & 63;
    int pt = blockIdx.x * 4 + w;
    const float* xp = X + (size_t)pt * H_;
    float s = 0.f;
    for (int k = lane; k < H_; k += 64) { float v = xp[k]; s += v * v; }
#pragma unroll
    for (int off = 32; off; off >>= 1) s += __shfl_down(s, off);
    if (lane == 0) sq[pt] = s;
}

// wave-per-row top-16 smallest (ties -> smaller index)
__global__ __launch_bounds__(256) void topk16(const float* __restrict__ D,
                                              int* __restrict__ idxb) {
    int w = threadIdx.x >> 6, lane = threadIdx.x & 63;
    int row = blockIdx.x * 4 + w;
    const float* dp = D + (size_t)row * N_;
    float lv[32];
#pragma unroll
    for (int t = 0; t < 32; ++t) lv[t] = dp[lane + (t << 6)];
    unsigned mask = 0;
    for (int it = 0; it < 16; ++it) {
        float bv = FLT_MAX;
        int bt = 0;
#pragma unroll
        for (int t = 0; t < 32; ++t) {
            bool ok = (((mask >> t) & 1u) == 0u) && (lv[t] < bv);
            bv = ok ? lv[t] : bv;
            bt = ok ? t : bt;
        }
        unsigned sb = __float_as_uint(bv);
        sb = (sb & 0x80000000u) ? ~sb : (sb | 0x80000000u);
        unsigned j = (unsigned)lane + ((unsigned)bt << 6);
        unsigned long long key = ((unsigned long long)sb << 32) | j;
#pragma unroll
        for (int off = 32; off; off >>= 1) {
            unsigned long long o = __shfl_xor(key, off);
            key = (o < key) ? o : key;
        }
        unsigned jw = (unsigned)(key & 0xffffffffu);
        if ((unsigned)lane == (jw & 63u)) mask |= 1u << (jw >> 6);
        if (lane == 0) idxb[row * 16 + it] = (int)jw;
    }
}

// t[b,i,h] = uv[row][h] + max_k uv[(b,idx_k)][256+h]
__global__ void gather_max(const float* __restrict__ uv, const int* __restrict__ idxb,
                           float* __restrict__ outp) {
    int row = blockIdx.x;
    int b = row >> 11;
    int h = threadIdx.x;
    const int* ip = idxb + row * 16;
    float m = -FLT_MAX;
#pragma unroll
    for (int k = 0; k < 16; ++k) {
        int j = ip[k];
        m = fmaxf(m, uv[((size_t)((b << 11) + j)) * 512 + 256 + h]);
    }
    outp[(size_t)row * H_ + h] = uv[(size_t)row * 512 + h] + m;
}

// ---- batchnorm over (B,N) per feature ----
__global__ void bn_zero(double* s) { s[threadIdx.x] = 0.0; }

__global__ void bn_stats(const float* __restrict__ X, double* __restrict__ sums) {
    int f = threadIdx.x;
    int r0 = blockIdx.x * 64;
    double s = 0.0, s2 = 0.0;
    for (int r = 0; r < 64; ++r) {
        float v = X[(size_t)(r0 + r) * H_ + f];
        s += v; s2 += (double)v * v;
    }
    atomicAdd(&sums[f], s);
    atomicAdd(&sums[H_ + f], s2);
}

__global__ void bn_final(const double* __restrict__ sums, const float* __restrict__ g,
                         const float* __restrict__ b, float* __restrict__ scsh) {
    int f = threadIdx.x;
    double m  = sums[f] / (double)BN_;
    double var = sums[H_ + f] / (double)BN_ - m * m;
    double inv = 1.0 / sqrt(var + 1e-5);
    float sc = g[f] * (float)inv;
    scsh[f] = sc;
    scsh[H_ + f] = b[f] - (float)m * sc;
}

// BN+ReLU, fused with split-bf16 packing. xbf32/Bq optional.
__global__ void bn_apply_pack(const float* __restrict__ X, const float* __restrict__ scsh,
                              float* __restrict__ xbf32, ushort_t* __restrict__ Ap,
                              ushort_t* __restrict__ Bq) {
    int row = blockIdx.x, f = threadIdx.x;
    float v = X[(size_t)row * H_ + f] * scsh[f] + scsh[H_ + f];
    v = fmaxf(v, 0.f);
    if (xbf32) xbf32[(size_t)row * H_ + f] = v;
    pack3(v, Ap, Bq, (size_t)row * KP_, f);
}

__global__ void residual_kernel(float* __restrict__ h, const float* __restrict__ t,
                                const float* __restrict__ alpha, int l) {
    size_t i = (size_t)blockIdx.x * H_ + threadIdx.x;
    h[i] += alpha[l] * t[i];
}

__global__ void maxpool1(const float* __restrict__ y, float* __restrict__ pmax) {
    int b = blockIdx.x, gc = blockIdx.y, nc = blockIdx.z;
    int g = gc * 256 + threadIdx.x;
    const float* yb = y + ((size_t)b * N_ + (size_t)nc * 128) * G_;
    float m = -FLT_MAX;
    for (int n = 0; n < 128; ++n) m = fmaxf(m, yb[(size_t)n * G_ + g]);
    pmax[((size_t)(b * 16 + nc)) * G_ + g] = m;
}

__global__ void maxpool2(const float* __restrict__ pmax, float* __restrict__ p) {
    int b = blockIdx.x;
    int g = blockIdx.y * 256 + threadIdx.x;
    float m = -FLT_MAX;
    for (int c = 0; c < 16; ++c) m = fmaxf(m, pmax[((size_t)(b * 16 + c)) * G_ + g]);
    p[(size_t)b * G_ + g] = m;
}

__global__ void small_gemm(const float* __restrict__ A, const float* __restrict__ W,
                           const float* __restrict__ bias, float* __restrict__ Cc,
                           int Kd, int Nd, int relu) {
    int m = blockIdx.x;
    int c = threadIdx.x;
    float acc = 0.f;
    for (int k = 0; k < Kd; ++k) acc += A[m * Kd + k] * W[(size_t)k * Nd + c];
    acc += bias[c];
    if (relu) acc = fmaxf(acc, 0.f);
    Cc[(size_t)m * Nd + c] = acc;
}

// ---------------- launch ----------------
extern "C" void kernel_launch(void* const* d_in, const int* in_sizes, int n_in,
                              void* d_out, int out_size, void* d_ws, size_t ws_size,
                              hipStream_t stream) {
    (void)in_sizes; (void)n_in; (void)out_size;
    if (ws_size < WS_NEEDED) return;

    const float* x    = (const float*)d_in[0];
    const float* Wf   = (const float*)d_in[2];
    const float* bfv  = (const float*)d_in[3];
    const float* Wnn  = (const float*)d_in[4];
    const float* bnn  = (const float*)d_in[5];
    const float* g1   = (const float*)d_in[6];
    const float* b1   = (const float*)d_in[7];
    const float* We   = (const float*)d_in[8];
    const float* be   = (const float*)d_in[9];
    const float* g2   = (const float*)d_in[10];
    const float* b2   = (const float*)d_in[11];
    const float* Wl   = (const float*)d_in[12];
    const float* bl   = (const float*)d_in[13];
    const float* alpha= (const float*)d_in[14];
    const float* gg   = (const float*)d_in[15];
    const float* bgb  = (const float*)d_in[16];
    const float* Wg   = (const float*)d_in[17];
    const float* bg2  = (const float*)d_in[18];
    const float* Wm1  = (const float*)d_in[19];
    const float* bm1  = (const float*)d_in[20];
    const float* Wm2  = (const float*)d_in[21];
    const float* bm2  = (const float*)d_in[22];
    const float* Wm3  = (const float*)d_in[23];
    const float* bm3  = (const float*)d_in[24];
    float* outp = (float*)d_out;

    char* ws = (char*)d_ws;
    float*    h    = (float*)(ws + OFF_H);
    ushort_t* Ap   = (ushort_t*)(ws + OFF_APACK);
    ushort_t* Bq   = (ushort_t*)(ws + OFF_BPACK);
    float*    sqb  = (float*)(ws + OFF_SQ);
    int*      idxb = (int*)  (ws + OFF_IDX);
    double*   stats= (double*)(ws + OFF_STATS);
    float*    scsh = (float*)(ws + OFF_SCSH);
    float*    bcat = (float*)(ws + OFF_BCAT);
    float*    p0   = (float*)(ws + OFF_P0);
    float*    p1   = (float*)(ws + OFF_P1);
    float*    p2   = (float*)(ws + OFF_P2);
    float*    dmat = (float*)(ws + OFF_D);
    float*    t    = (float*)(ws + OFF_T);
    float*    u    = (float*)(ws + OFF_U);
    float*    xb   = (float*)(ws + OFF_XB);
    float*    uv   = (float*)(ws + OFF_UV);
    float*    y    = (float*)(ws + OFF_UV);
    ushort_t* Qw   = (ushort_t*)(ws + OFF_QW);
    float*    pmax = (float*)(ws + OFF_PMAX);

    auto bn_pre = [&](const float* src, const float* g, const float* b) {
        hipLaunchKernelGGL(bn_zero, dim3(1), dim3(512), 0, stream, stats);
        hipLaunchKernelGGL(bn_stats, dim3(256), dim3(256), 0, stream, src, stats);
        hipLaunchKernelGGL(bn_final, dim3(1), dim3(256), 0, stream, stats, g, b, scsh);
    };

    // h = x@Wf+bf (+pack), t = h@Wnn+bnn via MFMA
    hipLaunchKernelGGL(feat_pack, dim3(BN_), dim3(256), 0, stream, x, Wf, bfv, h, Ap);
    hipLaunchKernelGGL(pack_wT, dim3(H_), dim3(256), 0, stream, Wnn, Qw, H_);
    hipLaunchKernelGGL(mfma_gemm, dim3(2, 128, 1), dim3(256), 0, stream,
                       Ap, Qw, bnn, t, KP_, H_, 0LL, 0LL, 0LL, 0LL, 0);

    for (int l = 0; l < L_; ++l) {
        const float* src1 = (l == 0) ? t : h;
        bn_pre(src1, g1 + l * H_, b1 + l * H_);
        hipLaunchKernelGGL(bn_apply_pack, dim3(BN_), dim3(256), 0, stream,
                           src1, scsh, xb, Ap, Bq);
        hipLaunchKernelGGL(sqnorm, dim3(BN_ / 4), dim3(256), 0, stream, xb, sqb);
        // gram: per batch  D = sq[j] - 2 * Xb . Xb^T
        hipLaunchKernelGGL(mfma_gemm, dim3(16, 16, 8), dim3(256), 0, stream,
                           Ap, Bq, sqb, dmat, KP_, N_,
                           (long long)N_ * KP_, (long long)N_ * KP_,
                           (long long)N_ * N_, (long long)N_, 1);
        hipLaunchKernelGGL(topk16, dim3(BN_ / 4), dim3(256), 0, stream, dmat, idxb);
        // fused u|v gemm (N=512)
        hipLaunchKernelGGL(pack_qcat, dim3(512), dim3(256), 0, stream,
                           We + (size_t)l * 2 * H_ * H_, be + (size_t)l * H_, Qw, bcat);
        hipLaunchKernelGGL(mfma_gemm, dim3(4, 128, 1), dim3(256), 0, stream,
                           Ap, Qw, bcat, uv, KP_, 512, 0LL, 0LL, 0LL, 0LL, 0);
        hipLaunchKernelGGL(gather_max, dim3(BN_), dim3(256), 0, stream, uv, idxb, t);
        // BN2 + Wl
        bn_pre(t, g2 + l * H_, b2 + l * H_);
        hipLaunchKernelGGL(bn_apply_pack, dim3(BN_), dim3(256), 0, stream,
                           t, scsh, (float*)nullptr, Ap, (ushort_t*)nullptr);
        hipLaunchKernelGGL(pack_wT, dim3(H_), dim3(256), 0, stream,
                           Wl + (size_t)l * H_ * H_, Qw, H_);
        hipLaunchKernelGGL(mfma_gemm, dim3(2, 128, 1), dim3(256), 0, stream,
                           Ap, Qw, bl + (size_t)l * H_, u, KP_, H_, 0LL, 0LL, 0LL, 0LL, 0);
        hipLaunchKernelGGL(residual_kernel, dim3(BN_), dim3(256), 0, stream, h, u, alpha, l);
    }

    // head
    bn_pre(h, gg, bgb);
    hipLaunchKernelGGL(bn_apply_pack, dim3(BN_), dim3(256), 0, stream,
                       h, scsh, (float*)nullptr, Ap, (ushort_t*)nullptr);
    hipLaunchKernelGGL(pack_wT, dim3(G_), dim3(256), 0, stream, Wg, Qw, G_);
    hipLaunchKernelGGL(mfma_gemm, dim3(4, 128, 1), dim3(256), 0, stream,
                       Ap, Qw, bg2, y, KP_, G_, 0LL, 0LL, 0LL, 0LL, 0);
    hipLaunchKernelGGL(maxpool1, dim3(8, 2, 16), dim3(256), 0, stream, y, pmax);
    hipLaunchKernelGGL(maxpool2, dim3(8, 2), dim3(256), 0, stream, pmax, p0);
    hipLaunchKernelGGL(small_gemm, dim3(8), dim3(256), 0, stream, p0, Wm1, bm1, p1, G_, M0_, 1);
    hipLaunchKernelGGL(small_gemm, dim3(8), dim3(128), 0, stream, p1, Wm2, bm2, p2, M0_, M1_, 1);
    hipLaunchKernelGGL(small_gemm, dim3(8), dim3(128), 0, stream, p2, Wm3, bm3, outp, M1_, C_, 0);
}

// Round 3
// 1509.657 us; speedup vs baseline: 1.6214x; 1.1281x over previous
//
#include <hip/hip_runtime.h>
#include <cfloat>

#define B_  8
#define N_  2048
#define H_  256
#define L_  4
#define K_  16
#define G_  512
#define M0_ 256
#define M1_ 128
#define C_  128
#define BN_ 16384   // B_*N_
#define KP_ 768     // packed split-bf16 K (3*H_)

typedef unsigned short ushort_t;
typedef __attribute__((ext_vector_type(8))) short short8;
typedef __attribute__((ext_vector_type(4))) float f32x4;

// ---------------- workspace layout (bytes) ----------------
#define OFF_H     ((size_t)0)            // 16 MB  h (fp32, persistent)
#define OFF_APACK ((size_t)16777216)     // 25.2 MB  P-pack [hi,lo,hi]
#define OFF_BPACK ((size_t)41943040)     // 25.2 MB  Q-pack [hi,hi,lo] (gram)
#define OFF_SQ    ((size_t)67108864)     // 64 KB
#define OFF_IDX   ((size_t)67174400)     // 1 MB
#define OFF_STATS ((size_t)68222976)     // 4 KB (512 doubles)
#define OFF_SCSH  ((size_t)68227072)     // 2 KB
#define OFF_BCAT  ((size_t)68229120)     // 2 KB
#define OFF_P0    ((size_t)68231168)     // 16 KB
#define OFF_P1    ((size_t)68247552)
#define OFF_P2    ((size_t)68255744)
#define OFF_D     ((size_t)69206016)     // 134.2 MB dmat; region multiplexed below
#define OFF_T     (OFF_D + (size_t)0)           // 16 MB (alive gather_max -> bn2)
#define OFF_XB    (OFF_D + (size_t)33554432)    // 16 MB (alive bn1 -> sqnorm)
#define OFF_UV    (OFF_D + (size_t)50331648)    // 33.5 MB (alive uv gemm -> gather); also y
#define OFF_QW    (OFF_D + (size_t)83886080)    // 0.79 MB weight packs (lazy, post-topk)
#define OFF_PMAX  (OFF_D + (size_t)84672512)    // 256 KB
#define WS_NEEDED ((size_t)203423744)

// ---------------- helpers ----------------
static __device__ __forceinline__ ushort_t f2bf(float f) {
    unsigned u = __float_as_uint(f);
    unsigned r = (u + 0x7fffu + ((u >> 16) & 1u)) >> 16;   // RNE
    return (ushort_t)r;
}
static __device__ __forceinline__ float bf2f(ushort_t h) {
    return __uint_as_float(((unsigned)h) << 16);
}
static __device__ __forceinline__ void pack3(float v, ushort_t* A, ushort_t* Bq,
                                             size_t base, int f) {
    ushort_t hi = f2bf(v);
    ushort_t lo = f2bf(v - bf2f(hi));
    A[base + f] = hi; A[base + H_ + f] = lo; A[base + 2 * H_ + f] = hi;
    if (Bq) { Bq[base + f] = hi; Bq[base + H_ + f] = hi; Bq[base + 2 * H_ + f] = lo; }
}

// ---------------- kernels ----------------

// h = x @ Wf + bf ; also pack h into Apack
__global__ void feat_pack(const float* __restrict__ x, const float* __restrict__ Wf,
                          const float* __restrict__ bfv, float* __restrict__ h,
                          ushort_t* __restrict__ Ap) {
    int pt = blockIdx.x;
    int f  = threadIdx.x;
    float x0 = x[pt * 3 + 0], x1 = x[pt * 3 + 1], x2 = x[pt * 3 + 2];
    float v = x0 * Wf[f] + x1 * Wf[H_ + f] + x2 * Wf[2 * H_ + f] + bfv[f];
    h[(size_t)pt * H_ + f] = v;
    pack3(v, Ap, nullptr, (size_t)pt * KP_, f);
}

// W (256 x Nd) -> Qpack (Nd x 768) rows [hi,hi,lo] of W^T
__global__ void pack_wT(const float* __restrict__ W, ushort_t* __restrict__ Qp, int Nd) {
    int n = blockIdx.x, k = threadIdx.x;
    float w = W[(size_t)k * Nd + n];
    ushort_t hi = f2bf(w), lo = f2bf(w - bf2f(hi));
    size_t base = (size_t)n * KP_;
    Qp[base + k] = hi; Qp[base + H_ + k] = hi; Qp[base + 2 * H_ + k] = lo;
}

// Qcat for fused u|v gemm: rows 0..255 = (We_a - We_b)^T, rows 256..511 = We_b^T
__global__ void pack_qcat(const float* __restrict__ We_l, const float* __restrict__ be_l,
                          ushort_t* __restrict__ Qp, float* __restrict__ bcat) {
    int n = blockIdx.x, k = threadIdx.x;
    float w;
    if (n < H_) w = We_l[(size_t)k * H_ + n] - We_l[(size_t)H_ * H_ + (size_t)k * H_ + n];
    else        w = We_l[(size_t)H_ * H_ + (size_t)k * H_ + (n - H_)];
    ushort_t hi = f2bf(w), lo = f2bf(w - bf2f(hi));
    size_t base = (size_t)n * KP_;
    Qp[base + k] = hi; Qp[base + H_ + k] = hi; Qp[base + 2 * H_ + k] = lo;
    if (k == 0) bcat[n] = (n < H_) ? be_l[n] : 0.f;
}

// ---- split-bf16 MFMA GEMM: out = P (M x K) . Q^T (N x K) ----
// mode 0: out[r][c] = acc + aux[c]                         (dense, aux = bias)
// mode 1: out[r][c] = aux[c] - 2*acc                       (gram,  aux = sq)
// mode 2: out[r][c] = resid[r][c] + alphap[aidx]*(acc+aux[c])   (fused residual)
__global__ __launch_bounds__(256) void mfma_gemm(
    const ushort_t* __restrict__ P, const ushort_t* __restrict__ Q,
    const float* __restrict__ aux, float* __restrict__ out,
    int Kd, int ldOut,
    long long strideP, long long strideQ, long long strideOut, long long strideAux,
    int mode, const float* __restrict__ resid, const float* __restrict__ alphap,
    int aidx) {
    __shared__ __align__(16) ushort_t As[128 * 32];
    __shared__ __align__(16) ushort_t Bs[128 * 32];
    int z = blockIdx.z;
    P   += (size_t)z * strideP;
    Q   += (size_t)z * strideQ;
    out += (size_t)z * strideOut;
    aux += (size_t)z * strideAux;
    int i0 = blockIdx.y * 128, j0 = blockIdx.x * 128;
    int tid = threadIdx.x;
    int lane = tid & 63, wave = tid >> 6;
    int wm = wave & 1, wn = wave >> 1;
    int m16 = lane & 15, kq = (lane >> 4) * 8;

    f32x4 acc[4][4];
    f32x4 zero = {0.f, 0.f, 0.f, 0.f};
#pragma unroll
    for (int i = 0; i < 4; ++i)
#pragma unroll
        for (int j = 0; j < 4; ++j) acc[i][j] = zero;

    int srow = tid >> 2;           // 0..63  (chunk row for s=0)
    int skc  = (tid & 3) * 8;      // k element offset of 16B chunk

    for (int k0 = 0; k0 < Kd; k0 += 32) {
#pragma unroll
        for (int s = 0; s < 2; ++s) {
            int row = srow + s * 64;
            const ushort_t* gpA = P + (size_t)(i0 + row) * Kd + k0 + skc;
            const ushort_t* gpB = Q + (size_t)(j0 + row) * Kd + k0 + skc;
            __builtin_amdgcn_global_load_lds(
                (const __attribute__((address_space(1))) void*)gpA,
                (__attribute__((address_space(3))) void*)(As + (size_t)(wave * 64 + s * 256) * 8),
                16, 0, 0);
            __builtin_amdgcn_global_load_lds(
                (const __attribute__((address_space(1))) void*)gpB,
                (__attribute__((address_space(3))) void*)(Bs + (size_t)(wave * 64 + s * 256) * 8),
                16, 0, 0);
        }
        __syncthreads();
        short8 af[4], bfr[4];
#pragma unroll
        for (int fi = 0; fi < 4; ++fi)
            af[fi] = *(const short8*)(As + (wm * 64 + fi * 16 + m16) * 32 + kq);
#pragma unroll
        for (int fj = 0; fj < 4; ++fj)
            bfr[fj] = *(const short8*)(Bs + (wn * 64 + fj * 16 + m16) * 32 + kq);
#pragma unroll
        for (int fi = 0; fi < 4; ++fi)
#pragma unroll
            for (int fj = 0; fj < 4; ++fj)
                acc[fi][fj] = __builtin_amdgcn_mfma_f32_16x16x32_bf16(
                    af[fi], bfr[fj], acc[fi][fj], 0, 0, 0);
        __syncthreads();
    }
    float alpha = (mode == 2) ? alphap[aidx] : 0.f;
    // C/D layout: col = lane&15, row = (lane>>4)*4 + reg
    int rbase = i0 + wm * 64 + (lane >> 4) * 4;
    int cbase = j0 + wn * 64 + m16;
#pragma unroll
    for (int fi = 0; fi < 4; ++fi) {
#pragma unroll
        for (int fj = 0; fj < 4; ++fj) {
            int c = cbase + fj * 16;
            float a = aux[c];
#pragma unroll
            for (int r = 0; r < 4; ++r) {
                int gr = rbase + fi * 16 + r;
                size_t oidx = (size_t)gr * ldOut + c;
                float val;
                if (mode == 1)      val = a - 2.f * acc[fi][fj][r];
                else if (mode == 2) val = resid[oidx] + alpha * (acc[fi][fj][r] + a);
                else                val = acc[fi][fj][r] + a;
                out[oidx] = val;
            }
        }
    }
}

// per-point squared norm (fp32 activations)
__global__ void sqnorm(const float* __restrict__ X, float* __restrict__ sq) {
    int w = threadIdx.x >> 6, lane = threadIdx.x & 63;
    int pt = blockIdx.x * 4 + w;
    const float* xp = X + (size_t)pt * H_;
    float s = 0.f;
    for (int k = lane; k < H_; k += 64) { float v = xp[k]; s += v * v; }
#pragma unroll
    for (int off = 32; off; off >>= 1) s += __shfl_down(s, off);
    if (lane == 0) sq[pt] = s;
}

// wave-per-row top-16 smallest (ties -> smaller index)
__global__ __launch_bounds__(256) void topk16(const float* __restrict__ D,
                                              int* __restrict__ idxb) {
    int w = threadIdx.x >> 6, lane = threadIdx.x & 63;
    int row = blockIdx.x * 4 + w;
    const float* dp = D + (size_t)row * N_;
    float lv[32];
#pragma unroll
    for (int t = 0; t < 32; ++t) lv[t] = dp[lane + (t << 6)];
    unsigned mask = 0;
    for (int it = 0; it < 16; ++it) {
        float bv = FLT_MAX;
        int bt = 0;
#pragma unroll
        for (int t = 0; t < 32; ++t) {
            bool ok = (((mask >> t) & 1u) == 0u) && (lv[t] < bv);
            bv = ok ? lv[t] : bv;
            bt = ok ? t : bt;
        }
        unsigned sb = __float_as_uint(bv);
        sb = (sb & 0x80000000u) ? ~sb : (sb | 0x80000000u);
        unsigned j = (unsigned)lane + ((unsigned)bt << 6);
        unsigned long long key = ((unsigned long long)sb << 32) | j;
#pragma unroll
        for (int off = 32; off; off >>= 1) {
            unsigned long long o = __shfl_xor(key, off);
            key = (o < key) ? o : key;
        }
        unsigned jw = (unsigned)(key & 0xffffffffu);
        if ((unsigned)lane == (jw & 63u)) mask |= 1u << (jw >> 6);
        if (lane == 0) idxb[row * 16 + it] = (int)jw;
    }
}

// t[b,i,h] = uv[row][h] + max_k uv[(b,idx_k)][256+h]
__global__ void gather_max(const float* __restrict__ uv, const int* __restrict__ idxb,
                           float* __restrict__ outp) {
    int row = blockIdx.x;
    int b = row >> 11;
    int h = threadIdx.x;
    const int* ip = idxb + row * 16;
    float m = -FLT_MAX;
#pragma unroll
    for (int k = 0; k < 16; ++k) {
        int j = ip[k];
        m = fmaxf(m, uv[((size_t)((b << 11) + j)) * 512 + 256 + h]);
    }
    outp[(size_t)row * H_ + h] = uv[(size_t)row * 512 + h] + m;
}

// ---- batchnorm over (B,N) per feature ----
__global__ void bn_zero(double* s) { s[threadIdx.x] = 0.0; }

__global__ void bn_stats(const float* __restrict__ X, double* __restrict__ sums) {
    int f = threadIdx.x;
    int r0 = blockIdx.x * 64;
    double s = 0.0, s2 = 0.0;
    for (int r = 0; r < 64; ++r) {
        float v = X[(size_t)(r0 + r) * H_ + f];
        s += v; s2 += (double)v * v;
    }
    atomicAdd(&sums[f], s);
    atomicAdd(&sums[H_ + f], s2);
}

__global__ void bn_final(const double* __restrict__ sums, const float* __restrict__ g,
                         const float* __restrict__ b, float* __restrict__ scsh) {
    int f = threadIdx.x;
    double m  = sums[f] / (double)BN_;
    double var = sums[H_ + f] / (double)BN_ - m * m;
    double inv = 1.0 / sqrt(var + 1e-5);
    float sc = g[f] * (float)inv;
    scsh[f] = sc;
    scsh[H_ + f] = b[f] - (float)m * sc;
}

// BN+ReLU, fused with split-bf16 packing. xbf32/Bq optional.
__global__ void bn_apply_pack(const float* __restrict__ X, const float* __restrict__ scsh,
                              float* __restrict__ xbf32, ushort_t* __restrict__ Ap,
                              ushort_t* __restrict__ Bq) {
    int row = blockIdx.x, f = threadIdx.x;
    float v = X[(size_t)row * H_ + f] * scsh[f] + scsh[H_ + f];
    v = fmaxf(v, 0.f);
    if (xbf32) xbf32[(size_t)row * H_ + f] = v;
    pack3(v, Ap, Bq, (size_t)row * KP_, f);
}

__global__ void maxpool1(const float* __restrict__ y, float* __restrict__ pmax) {
    int b = blockIdx.x, gc = blockIdx.y, nc = blockIdx.z;
    int g = gc * 256 + threadIdx.x;
    const float* yb = y + ((size_t)b * N_ + (size_t)nc * 128) * G_;
    float m = -FLT_MAX;
    for (int n = 0; n < 128; ++n) m = fmaxf(m, yb[(size_t)n * G_ + g]);
    pmax[((size_t)(b * 16 + nc)) * G_ + g] = m;
}

__global__ void maxpool2(const float* __restrict__ pmax, float* __restrict__ p) {
    int b = blockIdx.x;
    int g = blockIdx.y * 256 + threadIdx.x;
    float m = -FLT_MAX;
    for (int c = 0; c < 16; ++c) m = fmaxf(m, pmax[((size_t)(b * 16 + c)) * G_ + g]);
    p[(size_t)b * G_ + g] = m;
}

// parallel split-K head gemm: grid(M, Nd/64), 256 thr = 64 cols x 4 k-slices
__global__ __launch_bounds__(256) void head_gemm(const float* __restrict__ A,
                                                 const float* __restrict__ W,
                                                 const float* __restrict__ bias,
                                                 float* __restrict__ Cc,
                                                 int Kd, int Nd, int relu) {
    int m = blockIdx.x;
    int c0 = blockIdx.y * 64;
    int cl = threadIdx.x & 63;
    int ks = threadIdx.x >> 6;       // 0..3
    int kper = Kd >> 2;
    const float* Ap = A + (size_t)m * Kd + (size_t)ks * kper;
    const float* Wp = W + (size_t)ks * kper * Nd + c0 + cl;
    float acc = 0.f;
    for (int k = 0; k < kper; k += 8) {
#pragma unroll
        for (int u2 = 0; u2 < 8; ++u2)
            acc += Ap[k + u2] * Wp[(size_t)(k + u2) * Nd];
    }
    __shared__ float red[4][64];
    red[ks][cl] = acc;
    __syncthreads();
    if (ks == 0) {
        float s = red[0][cl] + red[1][cl] + red[2][cl] + red[3][cl] + bias[c0 + cl];
        if (relu) s = fmaxf(s, 0.f);
        Cc[(size_t)m * Nd + c0 + cl] = s;
    }
}

// ---------------- launch ----------------
extern "C" void kernel_launch(void* const* d_in, const int* in_sizes, int n_in,
                              void* d_out, int out_size, void* d_ws, size_t ws_size,
                              hipStream_t stream) {
    (void)in_sizes; (void)n_in; (void)out_size;
    if (ws_size < WS_NEEDED) return;

    const float* x    = (const float*)d_in[0];
    const float* Wf   = (const float*)d_in[2];
    const float* bfv  = (const float*)d_in[3];
    const float* Wnn  = (const float*)d_in[4];
    const float* bnn  = (const float*)d_in[5];
    const float* g1   = (const float*)d_in[6];
    const float* b1   = (const float*)d_in[7];
    const float* We   = (const float*)d_in[8];
    const float* be   = (const float*)d_in[9];
    const float* g2   = (const float*)d_in[10];
    const float* b2   = (const float*)d_in[11];
    const float* Wl   = (const float*)d_in[12];
    const float* bl   = (const float*)d_in[13];
    const float* alpha= (const float*)d_in[14];
    const float* gg   = (const float*)d_in[15];
    const float* bgb  = (const float*)d_in[16];
    const float* Wg   = (const float*)d_in[17];
    const float* bg2  = (const float*)d_in[18];
    const float* Wm1  = (const float*)d_in[19];
    const float* bm1  = (const float*)d_in[20];
    const float* Wm2  = (const float*)d_in[21];
    const float* bm2  = (const float*)d_in[22];
    const float* Wm3  = (const float*)d_in[23];
    const float* bm3  = (const float*)d_in[24];
    float* outp = (float*)d_out;

    char* ws = (char*)d_ws;
    float*    h    = (float*)(ws + OFF_H);
    ushort_t* Ap   = (ushort_t*)(ws + OFF_APACK);
    ushort_t* Bq   = (ushort_t*)(ws + OFF_BPACK);
    float*    sqb  = (float*)(ws + OFF_SQ);
    int*      idxb = (int*)  (ws + OFF_IDX);
    double*   stats= (double*)(ws + OFF_STATS);
    float*    scsh = (float*)(ws + OFF_SCSH);
    float*    bcat = (float*)(ws + OFF_BCAT);
    float*    p0   = (float*)(ws + OFF_P0);
    float*    p1   = (float*)(ws + OFF_P1);
    float*    p2   = (float*)(ws + OFF_P2);
    float*    dmat = (float*)(ws + OFF_D);
    float*    t    = (float*)(ws + OFF_T);
    float*    xb   = (float*)(ws + OFF_XB);
    float*    uv   = (float*)(ws + OFF_UV);
    float*    y    = (float*)(ws + OFF_UV);
    ushort_t* Qw   = (ushort_t*)(ws + OFF_QW);
    float*    pmax = (float*)(ws + OFF_PMAX);

    auto bn_pre = [&](const float* src, const float* g, const float* b) {
        hipLaunchKernelGGL(bn_zero, dim3(1), dim3(512), 0, stream, stats);
        hipLaunchKernelGGL(bn_stats, dim3(256), dim3(256), 0, stream, src, stats);
        hipLaunchKernelGGL(bn_final, dim3(1), dim3(256), 0, stream, stats, g, b, scsh);
    };

    // h = x@Wf+bf (+pack), t = h@Wnn+bnn via MFMA
    hipLaunchKernelGGL(feat_pack, dim3(BN_), dim3(256), 0, stream, x, Wf, bfv, h, Ap);
    hipLaunchKernelGGL(pack_wT, dim3(H_), dim3(256), 0, stream, Wnn, Qw, H_);
    hipLaunchKernelGGL(mfma_gemm, dim3(2, 128, 1), dim3(256), 0, stream,
                       Ap, Qw, bnn, t, KP_, H_, 0LL, 0LL, 0LL, 0LL, 0,
                       (const float*)nullptr, (const float*)nullptr, 0);

    for (int l = 0; l < L_; ++l) {
        const float* src1 = (l == 0) ? t : h;
        bn_pre(src1, g1 + l * H_, b1 + l * H_);
        hipLaunchKernelGGL(bn_apply_pack, dim3(BN_), dim3(256), 0, stream,
                           src1, scsh, xb, Ap, Bq);
        hipLaunchKernelGGL(sqnorm, dim3(BN_ / 4), dim3(256), 0, stream, xb, sqb);
        // gram: per batch  D = sq[j] - 2 * Xb . Xb^T
        hipLaunchKernelGGL(mfma_gemm, dim3(16, 16, 8), dim3(256), 0, stream,
                           Ap, Bq, sqb, dmat, KP_, N_,
                           (long long)N_ * KP_, (long long)N_ * KP_,
                           (long long)N_ * N_, (long long)N_, 1,
                           (const float*)nullptr, (const float*)nullptr, 0);
        hipLaunchKernelGGL(topk16, dim3(BN_ / 4), dim3(256), 0, stream, dmat, idxb);
        // fused u|v gemm (N=512)
        hipLaunchKernelGGL(pack_qcat, dim3(512), dim3(256), 0, stream,
                           We + (size_t)l * 2 * H_ * H_, be + (size_t)l * H_, Qw, bcat);
        hipLaunchKernelGGL(mfma_gemm, dim3(4, 128, 1), dim3(256), 0, stream,
                           Ap, Qw, bcat, uv, KP_, 512, 0LL, 0LL, 0LL, 0LL, 0,
                           (const float*)nullptr, (const float*)nullptr, 0);
        hipLaunchKernelGGL(gather_max, dim3(BN_), dim3(256), 0, stream, uv, idxb, t);
        // BN2 + Wl with fused residual: h = h + alpha[l]*(xb@Wl + bl)
        bn_pre(t, g2 + l * H_, b2 + l * H_);
        hipLaunchKernelGGL(bn_apply_pack, dim3(BN_), dim3(256), 0, stream,
                           t, scsh, (float*)nullptr, Ap, (ushort_t*)nullptr);
        hipLaunchKernelGGL(pack_wT, dim3(H_), dim3(256), 0, stream,
                           Wl + (size_t)l * H_ * H_, Qw, H_);
        hipLaunchKernelGGL(mfma_gemm, dim3(2, 128, 1), dim3(256), 0, stream,
                           Ap, Qw, bl + (size_t)l * H_, h, KP_, H_, 0LL, 0LL, 0LL, 0LL, 2,
                           h, alpha, l);
    }

    // head
    bn_pre(h, gg, bgb);
    hipLaunchKernelGGL(bn_apply_pack, dim3(BN_), dim3(256), 0, stream,
                       h, scsh, (float*)nullptr, Ap, (ushort_t*)nullptr);
    hipLaunchKernelGGL(pack_wT, dim3(G_), dim3(256), 0, stream, Wg, Qw, G_);
    hipLaunchKernelGGL(mfma_gemm, dim3(4, 128, 1), dim3(256), 0, stream,
                       Ap, Qw, bg2, y, KP_, G_, 0LL, 0LL, 0LL, 0LL, 0,
                       (const float*)nullptr, (const float*)nullptr, 0);
    hipLaunchKernelGGL(maxpool1, dim3(8, 2, 16), dim3(256), 0, stream, y, pmax);
    hipLaunchKernelGGL(maxpool2, dim3(8, 2), dim3(256), 0, stream, pmax, p0);
    hipLaunchKernelGGL(head_gemm, dim3(8, 4), dim3(256), 0, stream, p0, Wm1, bm1, p1, G_, M0_, 1);
    hipLaunchKernelGGL(head_gemm, dim3(8, 2), dim3(256), 0, stream, p1, Wm2, bm2, p2, M0_, M1_, 1);
    hipLaunchKernelGGL(head_gemm, dim3(8, 2), dim3(256), 0, stream, p2, Wm3, bm3, outp, M1_, C_, 0);
}